// Round 1
// baseline (501.594 us; speedup 1.0000x reference)
//
#include <hip/hip_runtime.h>
#include <math.h>

// Problem constants (from reference): B=64, L=256, H=64
#define PB 64
#define PL 256
#define PH 64
#define TEMP 0.07f
#define NEG_INF_F (-1e9f)

// Tiling: per block = one (b,c) pair. q-chunks and k-chunks of 128.
// 256 threads as 16 qgroups x 16 kgroups, each thread an 8x8 register tile.
#define QC 128
#define KC 128
#define LDS_W 132   // 128 + 4 pad, keeps 16B alignment for float4 reads

__global__ __launch_bounds__(256, 2)
void colbert_scores_kernel(const float* __restrict__ Qg,
                           const float* __restrict__ Kg,
                           const int*   __restrict__ qmask,
                           const int*   __restrict__ kmask,
                           float*       __restrict__ scores) {
    const int c = blockIdx.x;   // key batch index
    const int b = blockIdx.y;   // query batch index
    const int tid = threadIdx.x;

    __shared__ float Qs[PH][LDS_W];   // Qs[h][q_local]  (transposed)
    __shared__ float Ks[PH][LDS_W];   // Ks[h][k_local]  (transposed)
    __shared__ int   kmI[PL];
    __shared__ float qmF[PL];
    __shared__ float red[4];          // per-wave partials

    // Stage masks once.
    kmI[tid] = kmask[c * PL + tid];
    qmF[tid] = (float)qmask[b * PL + tid];

    const int qg = tid >> 4;          // 0..15
    const int kg = tid & 15;          // 0..15
    const int q0 = qg * 8;
    const int k0 = kg * 8;

    float partial = 0.0f;             // per-thread score contribution

    for (int qc = 0; qc < PL / QC; ++qc) {
        __syncthreads();              // previous Qs reads done (and masks visible)
        // Stage Q chunk, transposed: global is fully contiguous over (q,h).
        {
            const float* Qbase = Qg + ((size_t)b * PL + qc * QC) * PH;
            #pragma unroll
            for (int it = 0; it < (QC * PH) / (256 * 4); ++it) {
                int lin = it * 256 + tid;          // float4 index
                int q = lin >> 4;                  // PH/4 = 16 float4 per row
                int h4 = lin & 15;
                float4 v = *(const float4*)(Qbase + (size_t)lin * 4);
                Qs[h4 * 4 + 0][q] = v.x;
                Qs[h4 * 4 + 1][q] = v.y;
                Qs[h4 * 4 + 2][q] = v.z;
                Qs[h4 * 4 + 3][q] = v.w;
            }
        }

        float maxv[8];
        #pragma unroll
        for (int i = 0; i < 8; ++i) maxv[i] = NEG_INF_F;

        for (int kc = 0; kc < PL / KC; ++kc) {
            __syncthreads();          // previous Ks reads done; Qs writes visible after next sync
            {
                const float* Kbase = Kg + ((size_t)c * PL + kc * KC) * PH;
                #pragma unroll
                for (int it = 0; it < (KC * PH) / (256 * 4); ++it) {
                    int lin = it * 256 + tid;
                    int k = lin >> 4;
                    int h4 = lin & 15;
                    float4 v = *(const float4*)(Kbase + (size_t)lin * 4);
                    Ks[h4 * 4 + 0][k] = v.x;
                    Ks[h4 * 4 + 1][k] = v.y;
                    Ks[h4 * 4 + 2][k] = v.z;
                    Ks[h4 * 4 + 3][k] = v.w;
                }
            }
            __syncthreads();

            // GEMM: acc[8][8] += Q[q0..q0+7][h] * K[k0..k0+7][h]
            float acc[8][8];
            #pragma unroll
            for (int i = 0; i < 8; ++i)
                #pragma unroll
                for (int j = 0; j < 8; ++j) acc[i][j] = 0.0f;

            #pragma unroll 4
            for (int h = 0; h < PH; ++h) {
                float4 qa = *(const float4*)&Qs[h][q0];
                float4 qb = *(const float4*)&Qs[h][q0 + 4];
                float4 ka = *(const float4*)&Ks[h][k0];
                float4 kb = *(const float4*)&Ks[h][k0 + 4];
                float qr[8] = {qa.x, qa.y, qa.z, qa.w, qb.x, qb.y, qb.z, qb.w};
                float kr[8] = {ka.x, ka.y, ka.z, ka.w, kb.x, kb.y, kb.z, kb.w};
                #pragma unroll
                for (int i = 0; i < 8; ++i)
                    #pragma unroll
                    for (int j = 0; j < 8; ++j)
                        acc[i][j] += qr[i] * kr[j];
            }

            // Masked max update over this k-chunk.
            const int kbase = kc * KC + k0;
            int km[8];
            #pragma unroll
            for (int j = 0; j < 8; ++j) km[j] = kmI[kbase + j];
            #pragma unroll
            for (int i = 0; i < 8; ++i) {
                float mv = maxv[i];
                #pragma unroll
                for (int j = 0; j < 8; ++j) {
                    float s = km[j] ? acc[i][j] : NEG_INF_F;
                    mv = fmaxf(mv, s);
                }
                maxv[i] = mv;
            }
        }

        // Combine max across the 16 kgroups (contiguous lanes, width 16).
        #pragma unroll
        for (int i = 0; i < 8; ++i) {
            float mv = maxv[i];
            #pragma unroll
            for (int off = 8; off >= 1; off >>= 1)
                mv = fmaxf(mv, __shfl_xor(mv, off, 16));
            maxv[i] = mv;
        }

        if (kg == 0) {
            const int qbase = qc * QC + q0;
            #pragma unroll
            for (int i = 0; i < 8; ++i)
                partial += maxv[i] * qmF[qbase + i];
        }
    }

    // Block-wide sum of partial (non-kg0 lanes carry 0).
    #pragma unroll
    for (int off = 32; off >= 1; off >>= 1)
        partial += __shfl_xor(partial, off, 64);
    const int wid = tid >> 6;
    if ((tid & 63) == 0) red[wid] = partial;
    __syncthreads();
    if (tid == 0) {
        float total = red[0] + red[1] + red[2] + red[3];
        scores[b * PB + c] = total * (1.0f / TEMP);
    }
}

__global__ void finalize_kernel(const float* __restrict__ scores,
                                const int*   __restrict__ labels,
                                float*       __restrict__ out) {
    const int r = threadIdx.x;   // 64 threads, one per row
    const float* row = scores + r * PB;
    float mx = NEG_INF_F;
    for (int j = 0; j < PB; ++j) mx = fmaxf(mx, row[j]);
    float se = 0.0f;
    for (int j = 0; j < PB; ++j) se += expf(row[j] - mx);
    float logp_diag = row[r] - mx - logf(se);
    float w = (float)labels[r];
    float wd = w * logp_diag;
    #pragma unroll
    for (int off = 32; off >= 1; off >>= 1) {
        wd += __shfl_xor(wd, off, 64);
        w  += __shfl_xor(w,  off, 64);
    }
    if (r == 0) out[0] = -wd / fmaxf(w, 1.0f);
}

extern "C" void kernel_launch(void* const* d_in, const int* in_sizes, int n_in,
                              void* d_out, int out_size, void* d_ws, size_t ws_size,
                              hipStream_t stream) {
    const float* Q      = (const float*)d_in[0];  // (64,256,64) fp32
    const float* K      = (const float*)d_in[1];  // (64,256,64) fp32
    const int*   labels = (const int*)d_in[2];    // (64,) int32 (jax x64 disabled)
    const int*   qmask  = (const int*)d_in[3];    // (64,256) int32
    const int*   kmask  = (const int*)d_in[4];    // (64,256) int32
    float*       out    = (float*)d_out;          // scalar fp32
    float*       scores = (float*)d_ws;           // 64*64 fp32 scratch

    dim3 grid(PB, PB);   // x = c (key batch), y = b (query batch)
    colbert_scores_kernel<<<grid, 256, 0, stream>>>(Q, K, qmask, kmask, scores);
    finalize_kernel<<<1, 64, 0, stream>>>(scores, labels, out);
}

// Round 2
// 114.399 us; speedup vs baseline: 4.3846x; 4.3846x over previous
//
#include <hip/hip_runtime.h>
#include <math.h>

// Problem constants: B=64, L=256, H=64
#define PB 64
#define PL 256
#define PH 64
#define TEMP 0.07f
#define NEG_INF_F (-1e9f)

#define KSTRIDE 72   // bf16 elements per staged K row (64 + 8 pad; 144 B, 16B-aligned)

typedef short short8 __attribute__((ext_vector_type(8)));   // 8 bf16 bit-patterns
typedef float f32x4 __attribute__((ext_vector_type(4)));

// ---------------- fp32 -> bf16 (RTNE) convert kernel ----------------
__device__ __forceinline__ unsigned short f32_to_bf16(float f) {
    unsigned int u = __float_as_uint(f);
    u += 0x7FFFu + ((u >> 16) & 1u);    // round to nearest even
    return (unsigned short)(u >> 16);
}

__global__ void convert_kernel(const float* __restrict__ Q,
                               const float* __restrict__ K,
                               unsigned short* __restrict__ Qb,
                               unsigned short* __restrict__ Kb) {
    // 2 * (64*256*64) = 2M elements, vec4: 524288 threads
    const int t = blockIdx.x * blockDim.x + threadIdx.x;
    const int NV4 = (PB * PL * PH) / 4;   // 262144 per tensor
    const float4* src;
    unsigned short* dst;
    int i;
    if (t < NV4) { src = (const float4*)Q; dst = Qb; i = t; }
    else         { src = (const float4*)K; dst = Kb; i = t - NV4; }
    float4 v = src[i];
    ushort4 o;
    o.x = f32_to_bf16(v.x); o.y = f32_to_bf16(v.y);
    o.z = f32_to_bf16(v.z); o.w = f32_to_bf16(v.w);
    *(ushort4*)(dst + (size_t)i * 4) = o;
}

// ---------------- main scores kernel: one block per (b,c) ----------------
__global__ __launch_bounds__(256)
void colbert_scores_mfma(const unsigned short* __restrict__ Qb,
                         const unsigned short* __restrict__ Kb,
                         const int*   __restrict__ qmask,
                         const int*   __restrict__ kmask,
                         float*       __restrict__ scores) {
    const int c = blockIdx.x;
    const int b = blockIdx.y;
    const int tid  = threadIdx.x;
    const int wave = tid >> 6;
    const int lane = tid & 63;
    const int n    = lane & 15;        // col / row-within-tile index
    const int g    = (lane >> 4) & 3;  // quad index

    __shared__ __align__(16) unsigned short Ks[PL * KSTRIDE];  // 36 KB
    __shared__ int   kmI[PL];
    __shared__ float qmF[PL];
    __shared__ float red[4];

    // Stage masks
    kmI[tid] = kmask[c * PL + tid];
    qmF[tid] = (float)qmask[b * PL + tid];

    // Stage K_c (256 x 64 bf16) into LDS, padded stride.
    {
        const unsigned short* Kbase = Kb + ((size_t)c * PL) * PH;
        #pragma unroll
        for (int it = 0; it < (PL * PH) / (256 * 8); ++it) {   // 8 iters
            int lin = it * 256 + tid;          // 16B chunk index, 2048 total
            int row = lin >> 3;
            int off = lin & 7;
            ushort4 v0 = *(const ushort4*)(Kbase + (size_t)row * PH + off * 8);
            ushort4 v1 = *(const ushort4*)(Kbase + (size_t)row * PH + off * 8 + 4);
            *(ushort4*)(&Ks[row * KSTRIDE + off * 8])     = v0;
            *(ushort4*)(&Ks[row * KSTRIDE + off * 8 + 4]) = v1;
        }
    }

    // Load this wave's A-fragments (Q) straight from global into registers.
    // Wave handles q rows [wave*64, wave*64+64). A-frag layout (16x16x32):
    // lane holds A[m=lane&15][k=g*8+j], j=0..7.
    const int qw0 = wave * 64;
    short8 afrag[4][2];
    {
        const unsigned short* Qrow = Qb + ((size_t)b * PL) * PH;
        #pragma unroll
        for (int rt = 0; rt < 4; ++rt) {
            const unsigned short* p = Qrow + (size_t)(qw0 + rt * 16 + n) * PH + g * 8;
            afrag[rt][0] = *(const short8*)(p);
            afrag[rt][1] = *(const short8*)(p + 32);
        }
    }

    __syncthreads();   // Ks + masks visible

    // Running per-row masked max: maxv[rt][r] for row qw0 + rt*16 + g*4 + r
    float maxv[4][4];
    #pragma unroll
    for (int rt = 0; rt < 4; ++rt)
        #pragma unroll
        for (int r = 0; r < 4; ++r) maxv[rt][r] = NEG_INF_F;

    // 16 col-tiles of 16 k-tokens each
    for (int ct = 0; ct < 16; ++ct) {
        const int km = kmI[ct * 16 + n];   // this lane's column mask
        const unsigned short* krow = &Ks[(ct * 16 + n) * KSTRIDE + g * 8];
        short8 b0 = *(const short8*)(krow);
        short8 b1 = *(const short8*)(krow + 32);

        f32x4 acc[4];
        #pragma unroll
        for (int rt = 0; rt < 4; ++rt) acc[rt] = (f32x4){0.f, 0.f, 0.f, 0.f};
        #pragma unroll
        for (int rt = 0; rt < 4; ++rt)
            acc[rt] = __builtin_amdgcn_mfma_f32_16x16x32_bf16(afrag[rt][0], b0, acc[rt], 0, 0, 0);
        #pragma unroll
        for (int rt = 0; rt < 4; ++rt)
            acc[rt] = __builtin_amdgcn_mfma_f32_16x16x32_bf16(afrag[rt][1], b1, acc[rt], 0, 0, 0);

        // masked running max (C layout: col=lane&15, row=g*4+r)
        #pragma unroll
        for (int rt = 0; rt < 4; ++rt)
            #pragma unroll
            for (int r = 0; r < 4; ++r) {
                float s = km ? acc[rt][r] : NEG_INF_F;
                maxv[rt][r] = fmaxf(maxv[rt][r], s);
            }
    }

    // Max across the 16 lanes (cols) of each quad group.
    #pragma unroll
    for (int rt = 0; rt < 4; ++rt)
        #pragma unroll
        for (int r = 0; r < 4; ++r) {
            float mv = maxv[rt][r];
            mv = fmaxf(mv, __shfl_xor(mv, 1, 16));
            mv = fmaxf(mv, __shfl_xor(mv, 2, 16));
            mv = fmaxf(mv, __shfl_xor(mv, 4, 16));
            mv = fmaxf(mv, __shfl_xor(mv, 8, 16));
            maxv[rt][r] = mv;
        }

    // qmask-weighted sum; count each row once (n==0 lanes).
    float partial = 0.0f;
    if (n == 0) {
        #pragma unroll
        for (int rt = 0; rt < 4; ++rt)
            #pragma unroll
            for (int r = 0; r < 4; ++r) {
                int row = qw0 + rt * 16 + g * 4 + r;
                partial += maxv[rt][r] * qmF[row];
            }
    }
    // combine lanes 0,16,32,48
    partial += __shfl_xor(partial, 16, 64);
    partial += __shfl_xor(partial, 32, 64);
    if (lane == 0) red[wave] = partial;
    __syncthreads();
    if (tid == 0) {
        float total = red[0] + red[1] + red[2] + red[3];
        scores[b * PB + c] = total * (1.0f / TEMP);
    }
}

// ---------------- finalize: log-softmax CE ----------------
__global__ void finalize_kernel(const float* __restrict__ scores,
                                const int*   __restrict__ labels,
                                float*       __restrict__ out) {
    const int r = threadIdx.x;   // 64 threads, one per row
    const float* row = scores + r * PB;
    float mx = NEG_INF_F;
    for (int j = 0; j < PB; ++j) mx = fmaxf(mx, row[j]);
    float se = 0.0f;
    for (int j = 0; j < PB; ++j) se += expf(row[j] - mx);
    float logp_diag = row[r] - mx - logf(se);
    float w = (float)labels[r];
    float wd = w * logp_diag;
    #pragma unroll
    for (int off = 32; off >= 1; off >>= 1) {
        wd += __shfl_xor(wd, off, 64);
        w  += __shfl_xor(w,  off, 64);
    }
    if (r == 0) out[0] = -wd / fmaxf(w, 1.0f);
}

extern "C" void kernel_launch(void* const* d_in, const int* in_sizes, int n_in,
                              void* d_out, int out_size, void* d_ws, size_t ws_size,
                              hipStream_t stream) {
    const float* Q      = (const float*)d_in[0];
    const float* K      = (const float*)d_in[1];
    const int*   labels = (const int*)d_in[2];
    const int*   qmask  = (const int*)d_in[3];
    const int*   kmask  = (const int*)d_in[4];
    float*       out    = (float*)d_out;

    // ws layout: [scores 16KB][Qb 2MB][Kb 2MB]
    char* ws = (char*)d_ws;
    float*          scores = (float*)ws;
    unsigned short* Qb     = (unsigned short*)(ws + 16 * 1024);
    unsigned short* Kb     = (unsigned short*)(ws + 16 * 1024 + 2 * 1024 * 1024);

    const int total_v4 = 2 * (PB * PL * PH) / 4;   // 524288
    convert_kernel<<<total_v4 / 256, 256, 0, stream>>>(Q, K, Qb, Kb);

    dim3 grid(PB, PB);
    colbert_scores_mfma<<<grid, 256, 0, stream>>>(Qb, Kb, qmask, kmask, scores);
    finalize_kernel<<<1, 64, 0, stream>>>(scores, labels, out);
}